// Round 4
// baseline (63.560 us; speedup 1.0000x reference)
//
#include <hip/hip_runtime.h>

// MNIST_QNN_Classifier: analytic collapse of the reference circuit.
//
// e[b]^2 = prod_{l=0}^{11} g_l,  g_l = cos^2(a/2) or sin^2(a/2) by bit l of b,
//          a = alpha[(2^l - 1) + (b >> (12-l))].
//          Half-angle: cos^2(a/2) = 0.5 + 0.5*cos(a); sin^2 = 0.5 - 0.5*cos(a)
//          -> precompute h[i] = 0.5*cos(alpha[i]) (4095 nodes) into LDS once.
// qz[b] = v0^2+v1^2-v2^2-v3^2, v = first column of the 4x4 QNN unit
//         (4 layers: RY(t0) (x) RY(t1) then CNOT(0->1), all real).
// expv = sum_b e[b]^2 * qz[b];  out[0..63] = expv.
//
// Schedule: theta loads issued first (latency overlaps alpha staging); all
// transcendental work done pre-barrier; post-barrier is only the LDS tree
// product + FMA + reduction. Single block -- launch-latency regime.

#define MQ 12
#define NBLK 4096   // 2^MQ

__global__ __launch_bounds__(1024) void qnn_expv_kernel(
    const float* __restrict__ alpha,     // (4095,)
    const float* __restrict__ thetas,    // (4096, 8)
    float* __restrict__ out)             // (64,)
{
    __shared__ float s_h[NBLK - 1];      // 0.5*cos(alpha[node]), 16380 B
    __shared__ float s_part[16];

    const int tid = threadIdx.x;

    // (1) issue all theta loads up front (8x global_load_dwordx4, in flight
    //     under the staging work below)
    float4 th[4][2];
    #pragma unroll
    for (int k = 0; k < 4; ++k) {
        const size_t b = (size_t)(k * 1024 + tid);
        th[k][0] = *reinterpret_cast<const float4*>(thetas + b * 8);
        th[k][1] = *reinterpret_cast<const float4*>(thetas + b * 8 + 4);
    }

    // (2) stage 4095 node half-angle cosines (4 precise cosf per thread)
    for (int i = tid; i < NBLK - 1; i += 1024)
        s_h[i] = 0.5f * cosf(alpha[i]);

    // (3) QNN factor per item -- depends only on thetas, runs pre-barrier
    float qz[4];
    #pragma unroll
    for (int k = 0; k < 4; ++k) {
        const float tl[8] = {th[k][0].x, th[k][0].y, th[k][0].z, th[k][0].w,
                             th[k][1].x, th[k][1].y, th[k][1].z, th[k][1].w};
        float v0 = 1.0f, v1 = 0.0f, v2 = 0.0f, v3 = 0.0f;
        #pragma unroll
        for (int l = 0; l < 4; ++l) {
            float s0, c0, s1, c1;
            __sincosf(tl[2 * l] * 0.5f, &s0, &c0);
            __sincosf(tl[2 * l + 1] * 0.5f, &s1, &c1);
            // rot = RY(t0) (x) RY(t1); RY = [[c,-s],[s,c]]; index = q0*2+q1
            const float a01 = c1 * v0 - s1 * v1;
            const float b01 = s1 * v0 + c1 * v1;
            const float a23 = c1 * v2 - s1 * v3;
            const float b23 = s1 * v2 + c1 * v3;
            const float w0 = c0 * a01 - s0 * a23;
            const float w1 = c0 * b01 - s0 * b23;
            const float w2 = s0 * a01 + c0 * a23;
            const float w3 = s0 * b01 + c0 * b23;
            // CNOT(q0->q1): out[2] = in[3], out[3] = in[2]
            v0 = w0; v1 = w1; v2 = w3; v3 = w2;
        }
        qz[k] = v0 * v0 + v1 * v1 - v2 * v2 - v3 * v3;
    }

    __syncthreads();

    // (4) tree amplitude squared from the LDS table + accumulate
    float acc = 0.0f;
    #pragma unroll
    for (int k = 0; k < 4; ++k) {
        const int b = k * 1024 + tid;
        float e2 = 1.0f;
        #pragma unroll
        for (int l = 0; l < MQ; ++l) {
            const int node = (1 << l) - 1 + (b >> (MQ - l));
            const float h = s_h[node];
            const int bit = (b >> (MQ - 1 - l)) & 1;
            e2 *= bit ? (0.5f - h) : (0.5f + h);
        }
        acc += e2 * qz[k];
    }

    // (5) reduction: intra-wave shuffle, partials to LDS, wave 0 finishes
    #pragma unroll
    for (int off = 32; off > 0; off >>= 1)
        acc += __shfl_down(acc, off, 64);

    const int wave = tid >> 6;
    const int lane = tid & 63;
    if (lane == 0) s_part[wave] = acc;
    __syncthreads();

    if (wave == 0) {
        // each partial read 4x across 64 lanes; wave-sum then scale by 1/4
        float t = s_part[lane & 15];
        #pragma unroll
        for (int off = 32; off > 0; off >>= 1)
            t += __shfl_down(t, off, 64);
        t = __shfl(t, 0, 64) * 0.25f;    // broadcast total to all lanes
        out[lane] = t;
    }
}

extern "C" void kernel_launch(void* const* d_in, const int* in_sizes, int n_in,
                              void* d_out, int out_size, void* d_ws, size_t ws_size,
                              hipStream_t stream) {
    // d_in[0] = x (64,4) float32 -- unused (circuit is x-independent)
    const float* alpha  = (const float*)d_in[1];   // (4095,)
    const float* thetas = (const float*)d_in[2];   // (4096, 8)
    float* out = (float*)d_out;                    // (64,)

    qnn_expv_kernel<<<1, 1024, 0, stream>>>(alpha, thetas, out);
}

// Round 5
// 61.226 us; speedup vs baseline: 1.0381x; 1.0381x over previous
//
#include <hip/hip_runtime.h>

// MNIST_QNN_Classifier: analytic collapse of the reference circuit.
//
// e[b]^2 = prod_{l=0}^{11} g_l,  g_l = cos^2(a/2) or sin^2(a/2) by bit l of b,
//          a = alpha[(2^l - 1) + (b >> (12-l))].
//          Half-angle: cos^2(a/2) = 0.5 + 0.5*cos(a); sin^2 = 0.5 - 0.5*cos(a).
// qz[b] = v0^2+v1^2-v2^2-v3^2, v = first column of the 4x4 QNN unit
//         (4 layers: RY(t0) (x) RY(t1) then CNOT(0->1), all real).
// expv = sum_b e[b]^2 * qz[b];  out[0..63] = expv.
//
// Structure: 64 blocks x 1 wave, one item per thread, all-register (no LDS,
// no barrier); per-block partial -> ws; tiny finish kernel broadcasts total.
// Measured round 4: harness reset (256MB ws poison @ 40us, 85% HBM peak)
// dominates dur_us=63.6; this round minimizes the kernel-side remainder.

#define MQ 12
#define NBLK 4096   // 2^MQ

__global__ __launch_bounds__(64) void qnn_partial_kernel(
    const float* __restrict__ alpha,     // (4095,)
    const float* __restrict__ thetas,    // (4096, 8)
    float* __restrict__ partial)         // (64,) in ws
{
    const int b = blockIdx.x * 64 + threadIdx.x;

    // issue theta loads first; latency hides under the tree cosines
    const float4 th0 = *reinterpret_cast<const float4*>(thetas + (size_t)b * 8);
    const float4 th1 = *reinterpret_cast<const float4*>(thetas + (size_t)b * 8 + 4);

    // --- tree amplitude squared: 12 path nodes, half-angle identity ---
    float e2 = 1.0f;
    #pragma unroll
    for (int l = 0; l < MQ; ++l) {
        const int node = (1 << l) - 1 + (b >> (MQ - l));
        const float h = 0.5f * cosf(alpha[node]);   // precise; same values as passing round
        const int bit = (b >> (MQ - 1 - l)) & 1;
        e2 *= bit ? (0.5f - h) : (0.5f + h);
    }

    // --- first column of the 4-layer 2-qubit QNN unit ---
    const float tl[8] = {th0.x, th0.y, th0.z, th0.w, th1.x, th1.y, th1.z, th1.w};
    float v0 = 1.0f, v1 = 0.0f, v2 = 0.0f, v3 = 0.0f;
    #pragma unroll
    for (int l = 0; l < 4; ++l) {
        float s0, c0, s1, c1;
        __sincosf(tl[2 * l] * 0.5f, &s0, &c0);
        __sincosf(tl[2 * l + 1] * 0.5f, &s1, &c1);
        // rot = RY(t0) (x) RY(t1); RY = [[c,-s],[s,c]]; index = q0*2+q1
        const float a01 = c1 * v0 - s1 * v1;
        const float b01 = s1 * v0 + c1 * v1;
        const float a23 = c1 * v2 - s1 * v3;
        const float b23 = s1 * v2 + c1 * v3;
        const float w0 = c0 * a01 - s0 * a23;
        const float w1 = c0 * b01 - s0 * b23;
        const float w2 = s0 * a01 + c0 * a23;
        const float w3 = s0 * b01 + c0 * b23;
        // CNOT(q0->q1): out[2] = in[3], out[3] = in[2]
        v0 = w0; v1 = w1; v2 = w3; v3 = w2;
    }
    const float qz = v0 * v0 + v1 * v1 - v2 * v2 - v3 * v3;

    // --- per-wave partial ---
    float acc = e2 * qz;
    #pragma unroll
    for (int off = 32; off > 0; off >>= 1)
        acc += __shfl_down(acc, off, 64);

    if (threadIdx.x == 0) partial[blockIdx.x] = acc;
}

__global__ __launch_bounds__(64) void qnn_finish_kernel(
    const float* __restrict__ partial,   // (64,) in ws
    float* __restrict__ out)             // (64,)
{
    float t = partial[threadIdx.x];
    #pragma unroll
    for (int off = 32; off > 0; off >>= 1)
        t += __shfl_down(t, off, 64);
    t = __shfl(t, 0, 64);                // broadcast total to all 64 lanes
    out[threadIdx.x] = t;
}

extern "C" void kernel_launch(void* const* d_in, const int* in_sizes, int n_in,
                              void* d_out, int out_size, void* d_ws, size_t ws_size,
                              hipStream_t stream) {
    // d_in[0] = x (64,4) float32 -- unused (circuit is x-independent)
    const float* alpha  = (const float*)d_in[1];   // (4095,)
    const float* thetas = (const float*)d_in[2];   // (4096, 8)
    float* out     = (float*)d_out;                // (64,)
    float* partial = (float*)d_ws;                 // 64 floats of scratch

    qnn_partial_kernel<<<64, 64, 0, stream>>>(alpha, thetas, partial);
    qnn_finish_kernel<<<1, 64, 0, stream>>>(partial, out);
}